// Round 4
// baseline (755.998 us; speedup 1.0000x reference)
//
#include <hip/hip_runtime.h>

// RetinaNet decode + per-class NMS (exact reference semantics).
// Pipeline: memset(meta 96B) -> k_map (LDS-transposed decode+select+compact)
//           -> k_nms (sort+walk) -> k_fallback (exact, no-op unless flagged)
#define NB 8
#define NA 76725
#define NC 80
#define MAXDET 100
#define CAP  1024          // compaction buffer capacity per image
#define FTHR 0x3F7FF994u   // float bits of ~0.999902: E[count]/image ~600 (max of 80 U(0,1))
#define TILE 64            // anchors per block in k_map
#define ST4  21            // LDS row stride in float4 (84 dwords = 80 + 4 pad)

__device__ inline unsigned long long shfl_down_u64(unsigned long long v, int o) {
    unsigned lo = (unsigned)v, hi = (unsigned)(v >> 32);
    lo = __shfl_down(lo, o);
    hi = __shfl_down(hi, o);
    return ((unsigned long long)hi << 32) | lo;
}

__device__ inline unsigned long long shfl_xor_u64(unsigned long long v, int m) {
    unsigned lo = __shfl_xor((unsigned)v, m), hi = __shfl_xor((unsigned)(v >> 32), m);
    return ((unsigned long long)hi << 32) | lo;
}

__device__ inline bool iou_ge_half(float ax1, float ay1, float ax2, float ay2, float aar,
                                   float bx1, float by1, float bx2, float by2, float bar) {
    float xx1 = fmaxf(ax1, bx1), yy1 = fmaxf(ay1, by1);
    float xx2 = fminf(ax2, bx2), yy2 = fminf(ay2, by2);
    float inter = fmaxf(xx2 - xx1, 0.0f) * fmaxf(yy2 - yy1, 0.0f);
    float un = aar + bar - inter;             // commutative add: matches ref exactly
    float iou = (un > 0.0f) ? inter / un : 0.0f;
    return iou >= 0.5f;
}

// ---- Kernel 1: 64-anchor tile per block. Coalesced global->LDS stage of cls,
//      4-thread/anchor argmax from LDS, decode+emit+compact on t==0 lanes.
__global__ __launch_bounds__(256) void k_map(const float* __restrict__ cls,
                                             const float* __restrict__ reg,
                                             const float* __restrict__ anc,
                                             unsigned long long* __restrict__ keys,
                                             unsigned long long* __restrict__ boxes,
                                             ulonglong2* __restrict__ cand,
                                             unsigned int* __restrict__ cnt,
                                             unsigned int* __restrict__ vcnt) {
    __shared__ float4 sc[TILE * ST4];   // 21504 B
    const int b = blockIdx.y;
    const int n0 = blockIdx.x * TILE;
    const int ait = min(TILE, NA - n0);
    const int tid = threadIdx.x;
    const size_t base4 = ((size_t)b * NA + n0) * (NC / 4);
    const int nq = ait * (NC / 4);

    // stage: 5 lane-contiguous float4 loads per thread -> LDS (padded rows)
#pragma unroll
    for (int k = 0; k < 5; ++k) {
        int q = tid + k * 256;
        if (q < nq) {
            float4 v = reinterpret_cast<const float4*>(cls)[base4 + q];
            sc[(q / 20) * ST4 + (q % 20)] = v;
        }
    }
    __syncthreads();

    // quarter-reduce: 4 threads per anchor, 20 classes each (5x ds_read_b128)
    const int a = tid >> 2, t = tid & 3;
    float best = -1.0f; int bc = 0;
#pragma unroll
    for (int j = 0; j < 5; ++j) {
        float4 v = sc[a * ST4 + t * 5 + j];
        if (v.x > best) { best = v.x; bc = t * 20 + 4 * j + 0; }
        if (v.y > best) { best = v.y; bc = t * 20 + 4 * j + 1; }
        if (v.z > best) { best = v.z; bc = t * 20 + 4 * j + 2; }
        if (v.w > best) { best = v.w; bc = t * 20 + 4 * j + 3; }
    }
    // pack: non-negative scores -> bits monotone; tie -> smallest class wins
    unsigned long long pk = ((unsigned long long)__float_as_uint(best) << 8)
                          | (unsigned)(255 - bc);
    pk = max(pk, shfl_xor_u64(pk, 1));
    pk = max(pk, shfl_xor_u64(pk, 2));

    bool valid = false, sel = false;
    unsigned long long key = 0ull, bp = 0ull;
    if (t == 0 && a < ait) {
        unsigned sbits = (unsigned)(pk >> 8);
        int cg = 255 - (int)(pk & 0xFFull);
        const int n_img = n0 + a;
        const size_t n = (size_t)b * NA + n_img;
        float4 rg = reinterpret_cast<const float4*>(reg)[n];
        float4 an = reinterpret_cast<const float4*>(anc)[n];

        // decode — _rn intrinsics to forbid FMA contraction (match XLA mul+add).
        // Byte-identical to R1/R2 (verified absmax=0.0).
        float wx = __fsub_rn(an.z, an.x);
        float wy = __fsub_rn(an.w, an.y);
        float cx = __fadd_rn(an.x, __fmul_rn(0.5f, wx));
        float cy = __fadd_rn(an.y, __fmul_rn(0.5f, wy));
        float tx = __fmul_rn(rg.x, 0.1f), ty = __fmul_rn(rg.y, 0.1f);
        float tw = __fmul_rn(rg.z, 0.2f), th = __fmul_rn(rg.w, 0.2f);
        float pw = __fmul_rn(expf(tw), wx);
        float ph = __fmul_rn(expf(th), wy);
        float px = __fadd_rn(__fmul_rn(tx, wx), cx);
        float py = __fadd_rn(__fmul_rn(ty, wy), cy);
        int x1 = (int)__fsub_rn(px, __fmul_rn(0.5f, pw));
        int y1 = (int)__fsub_rn(py, __fmul_rn(0.5f, ph));
        int x2 = (int)__fadd_rn(px, __fmul_rn(0.5f, pw));
        int y2 = (int)__fadd_rn(py, __fmul_rn(0.5f, ph));
        x1 = max(x1, 0); y1 = max(y1, 0); x2 = min(x2, 639); y2 = min(y2, 639);

        bp = (unsigned long long)(unsigned short)(short)x1
           | ((unsigned long long)(unsigned short)(short)y1 << 16)
           | ((unsigned long long)(unsigned short)(short)x2 << 32)
           | ((unsigned long long)(unsigned short)(short)y2 << 48);
        float bestf = __uint_as_float(sbits);
        if (bestf > 0.05f) {  // MIN_SCORE strict
            unsigned inv = 0x1FFFFu - (unsigned)n_img;  // index asc tie-break under desc sort
            key = ((unsigned long long)sbits << 32) | ((unsigned long long)inv << 7)
                | (unsigned)cg;
            valid = true;
            sel = sbits >= FTHR;
        }
        keys[n] = key;
        boxes[n] = bp;
    }

    const int lane = tid & 63;
    unsigned long long bal = __ballot(valid);
    if (lane == 0 && bal) atomicAdd(&vcnt[b], (unsigned)__popcll(bal));

    unsigned long long sbal = __ballot(sel);
    unsigned base = 0;
    if (lane == 0 && sbal) base = atomicAdd(&cnt[b], (unsigned)__popcll(sbal));
    base = __shfl(base, 0);
    if (sel) {
        unsigned off = base + (unsigned)__popcll(sbal & ((1ull << lane) - 1ull));
        if (off < CAP) {
            ulonglong2 e; e.x = key; e.y = bp;
            cand[(size_t)b * CAP + off] = e;
        }
    }
}

// ---- Kernel 2: per-image bitonic sort (LDS, 1 cmp/thread/pass) + greedy walk + emit
__global__ __launch_bounds__(512) void k_nms(const ulonglong2* __restrict__ cand,
                                             const unsigned int* __restrict__ cnt,
                                             const unsigned int* __restrict__ vcnt,
                                             unsigned int* __restrict__ flag,
                                             float* __restrict__ out) {
    __shared__ unsigned long long sk[CAP];
    __shared__ unsigned long long sb[CAP];
    __shared__ int s_np;
    const int b = blockIdx.x;
    unsigned total = cnt[b];
    bool overflow = total > CAP;
    unsigned m = overflow ? CAP : total;

    for (int i = threadIdx.x; i < CAP; i += 512) {
        if (i < (int)m) { ulonglong2 e = cand[(size_t)b * CAP + i]; sk[i] = e.x; sb[i] = e.y; }
        else            { sk[i] = 0ull; sb[i] = 0ull; }
    }
    __syncthreads();

    // bitonic sort, descending by key; 512 threads = exactly one pair each
    for (int k = 2; k <= CAP; k <<= 1) {
        for (int j = k >> 1; j > 0; j >>= 1) {
            int t = threadIdx.x;
            int i = ((t & ~(j - 1)) << 1) | (t & (j - 1));
            int l = i | j;
            unsigned long long ki = sk[i], kl = sk[l];
            bool desc = (i & k) == 0;
            if (desc ? (ki < kl) : (ki > kl)) {
                sk[i] = kl; sk[l] = ki;
                unsigned long long tmp = sb[i]; sb[i] = sb[l]; sb[l] = tmp;
            }
            __syncthreads();
        }
    }

    // greedy walk on wave 0; picked state distributed in registers (2 slots/lane);
    // next key/box prefetched to hide LDS latency
    if (threadIdx.x < 64) {
        const int lane = threadIdx.x;
        float q0x1 = 0, q0y1 = 0, q0x2 = 0, q0y2 = 0, q0a = 0; int q0c = -1;
        float q1x1 = 0, q1y1 = 0, q1x2 = 0, q1y2 = 0, q1a = 0; int q1c = -1;
        int np = 0;
        unsigned long long nk = (m > 0) ? sk[0] : 0ull;
        unsigned long long nbx = (m > 0) ? sb[0] : 0ull;
        for (int jj = 0; jj < (int)m && np < MAXDET; ++jj) {
            unsigned long long key = nk;
            unsigned long long bx = nbx;
            if (jj + 1 < (int)m) { nk = sk[jj + 1]; nbx = sb[jj + 1]; }
            if (!key) break;
            int ci = (int)(key & 0x7Full);
            float x1 = (float)(short)(bx & 0xFFFF);
            float y1 = (float)(short)((bx >> 16) & 0xFFFF);
            float x2 = (float)(short)((bx >> 32) & 0xFFFF);
            float y2 = (float)(short)((bx >> 48) & 0xFFFF);
            float ar = (x2 - x1) * (y2 - y1);
            bool sup = false;
            if (lane < np && q0c == ci)
                sup = iou_ge_half(q0x1, q0y1, q0x2, q0y2, q0a, x1, y1, x2, y2, ar);
            if (64 + lane < np && q1c == ci)
                sup = sup || iou_ge_half(q1x1, q1y1, q1x2, q1y2, q1a, x1, y1, x2, y2, ar);
            if (__ballot(sup) != 0ull) continue;
            int s = np;
            if (s < 64) {
                if (lane == s) {
                    q0x1 = x1; q0y1 = y1; q0x2 = x2; q0y2 = y2; q0a = ar; q0c = ci;
                    out[b * MAXDET + s] = __uint_as_float((unsigned)(key >> 32));
                    out[NB * MAXDET + b * MAXDET + s] = (float)ci;
                    float* ob = out + 2 * NB * MAXDET + (size_t)(b * MAXDET + s) * 4;
                    ob[0] = x1; ob[1] = y1; ob[2] = x2; ob[3] = y2;
                }
            } else {
                if (lane == s - 64) {
                    q1x1 = x1; q1y1 = y1; q1x2 = x2; q1y2 = y2; q1a = ar; q1c = ci;
                    out[b * MAXDET + s] = __uint_as_float((unsigned)(key >> 32));
                    out[NB * MAXDET + b * MAXDET + s] = (float)ci;
                    float* ob = out + 2 * NB * MAXDET + (size_t)(b * MAXDET + s) * 4;
                    ob[0] = x1; ob[1] = y1; ob[2] = x2; ob[3] = y2;
                }
            }
            ++np;
        }
        if (lane == 0) s_np = np;
    }
    __syncthreads();
    int np = s_np;
    // fallback iff candidates were dropped (overflow) or walk exhausted with unseen valid cands
    bool fb = overflow || (np < MAXDET && vcnt[b] > m);
    if (threadIdx.x == 0) flag[b] = fb ? 1u : 0u;
    if (!fb) {
        for (int i = np + (int)threadIdx.x; i < MAXDET; i += 512) {
            out[b * MAXDET + i] = -1.0f;
            out[NB * MAXDET + b * MAXDET + i] = -1.0f;
            float* ob = out + 2 * NB * MAXDET + (size_t)(b * MAXDET + i) * 4;
            ob[0] = -1.0f; ob[1] = -1.0f; ob[2] = -1.0f; ob[3] = -1.0f;
        }
    }
}

// ---- Kernel 3: exact slow fallback (reference algorithm); no-op unless flag[b]
__global__ __launch_bounds__(1024) void k_fallback(unsigned long long* __restrict__ keys,
                                                   const unsigned long long* __restrict__ boxes,
                                                   const unsigned int* __restrict__ flag,
                                                   float* __restrict__ out) {
    const int b = blockIdx.x;
    if (!flag[b]) return;
    __shared__ unsigned long long wm[16];
    __shared__ unsigned long long gbest;
    unsigned long long* kb = keys + (size_t)b * NA;
    const unsigned long long* bb = boxes + (size_t)b * NA;

    for (int it = 0; it < MAXDET; ++it) {
        unsigned long long best = 0ull;
        for (int i = threadIdx.x; i < NA; i += 1024) {
            unsigned long long k = kb[i];
            if (k > best) best = k;
        }
        for (int o = 32; o > 0; o >>= 1) {
            unsigned long long v = shfl_down_u64(best, o);
            if (v > best) best = v;
        }
        if ((threadIdx.x & 63) == 0) wm[threadIdx.x >> 6] = best;
        __syncthreads();
        if (threadIdx.x == 0) {
            unsigned long long g = wm[0];
            for (int w = 1; w < 16; ++w) if (wm[w] > g) g = wm[w];
            gbest = g;
        }
        __syncthreads();
        best = gbest;
        if (best == 0ull) {
            for (int s = it + (int)threadIdx.x; s < MAXDET; s += 1024) {
                out[b * MAXDET + s] = -1.0f;
                out[NB * MAXDET + b * MAXDET + s] = -1.0f;
                float* ob = out + 2 * NB * MAXDET + (size_t)(b * MAXDET + s) * 4;
                ob[0] = -1.0f; ob[1] = -1.0f; ob[2] = -1.0f; ob[3] = -1.0f;
            }
            break;
        }
        int ci = (int)(best & 0x7Full);
        int a = 0x1FFFF - (int)((best >> 7) & 0x1FFFFull);
        unsigned long long bx = bb[a];
        float x1 = (float)(short)(bx & 0xFFFF);
        float y1 = (float)(short)((bx >> 16) & 0xFFFF);
        float x2 = (float)(short)((bx >> 32) & 0xFFFF);
        float y2 = (float)(short)((bx >> 48) & 0xFFFF);
        float ar = (x2 - x1) * (y2 - y1);
        if (threadIdx.x == 0) {
            out[b * MAXDET + it] = __uint_as_float((unsigned)(best >> 32));
            out[NB * MAXDET + b * MAXDET + it] = (float)ci;
            float* ob = out + 2 * NB * MAXDET + (size_t)(b * MAXDET + it) * 4;
            ob[0] = x1; ob[1] = y1; ob[2] = x2; ob[3] = y2;
        }
        for (int i = threadIdx.x; i < NA; i += 1024) {
            unsigned long long kk = kb[i];
            if (!kk) continue;
            if (kk == best) { kb[i] = 0ull; continue; }
            if ((int)(kk & 0x7Full) != ci) continue;
            unsigned long long ob2 = bb[i];
            float u1 = (float)(short)(ob2 & 0xFFFF);
            float v1 = (float)(short)((ob2 >> 16) & 0xFFFF);
            float u2 = (float)(short)((ob2 >> 32) & 0xFFFF);
            float v2 = (float)(short)((ob2 >> 48) & 0xFFFF);
            float oar = (u2 - u1) * (v2 - v1);
            if (iou_ge_half(x1, y1, x2, y2, ar, u1, v1, u2, v2, oar)) kb[i] = 0ull;
        }
        __syncthreads();
    }
}

extern "C" void kernel_launch(void* const* d_in, const int* in_sizes, int n_in,
                              void* d_out, int out_size, void* d_ws, size_t ws_size,
                              hipStream_t stream) {
    const float* cls = (const float*)d_in[0];
    const float* reg = (const float*)d_in[1];
    const float* anc = (const float*)d_in[2];
    float* out = (float*)d_out;

    const size_t SZ_KEYS = (size_t)NB * NA * 8;               // 4,910,400 B
    unsigned long long* keys  = (unsigned long long*)d_ws;
    unsigned long long* boxes = (unsigned long long*)((char*)d_ws + SZ_KEYS);
    ulonglong2* cand = (ulonglong2*)((char*)d_ws + 2 * SZ_KEYS);          // 16-aligned
    unsigned* cnt  = (unsigned*)((char*)d_ws + 2 * SZ_KEYS + (size_t)NB * CAP * 16);
    unsigned* vcnt = cnt + NB;
    unsigned* flag = vcnt + NB;

    // zero meta (cnt + vcnt + flag = 96 B)
    hipMemsetAsync(cnt, 0, 3 * NB * 4, stream);

    dim3 gmap((NA + TILE - 1) / TILE, NB);
    k_map<<<gmap, 256, 0, stream>>>(cls, reg, anc, keys, boxes, cand, cnt, vcnt);
    k_nms<<<NB, 512, 0, stream>>>(cand, cnt, vcnt, flag, out);
    k_fallback<<<NB, 1024, 0, stream>>>(keys, boxes, flag, out);
}

// Round 5
// 333.780 us; speedup vs baseline: 2.2650x; 2.2650x over previous
//
#include <hip/hip_runtime.h>

// RetinaNet decode + per-class NMS (exact reference semantics).
// Pipeline: memset(cnt_p 1KB) -> k_map (LDS-staged decode+select+compact, NO same-line atomics)
//           -> k_nms (vsum + sort + walk) -> k_fallback (exact, no-op unless flagged)
#define NB 8
#define NA 76725
#define NC 80
#define MAXDET 100
#define CAP  1024          // compaction buffer capacity per image
#define FTHR 0x3F7FF994u   // float bits of ~0.999902: E[count]/image ~600 (max of 80 U(0,1))
#define TILE 64            // anchors per block in k_map
#define NBLK 1199          // (NA + TILE - 1) / TILE
#define ST4  21            // LDS row stride in float4 (84 dwords = 80 + 4 pad)

__device__ inline unsigned long long shfl_down_u64(unsigned long long v, int o) {
    unsigned lo = (unsigned)v, hi = (unsigned)(v >> 32);
    lo = __shfl_down(lo, o);
    hi = __shfl_down(hi, o);
    return ((unsigned long long)hi << 32) | lo;
}

__device__ inline unsigned long long shfl_xor_u64(unsigned long long v, int m) {
    unsigned lo = __shfl_xor((unsigned)v, m), hi = __shfl_xor((unsigned)(v >> 32), m);
    return ((unsigned long long)hi << 32) | lo;
}

__device__ inline bool iou_ge_half(float ax1, float ay1, float ax2, float ay2, float aar,
                                   float bx1, float by1, float bx2, float by2, float bar) {
    float xx1 = fmaxf(ax1, bx1), yy1 = fmaxf(ay1, by1);
    float xx2 = fminf(ax2, bx2), yy2 = fminf(ay2, by2);
    float inter = fmaxf(xx2 - xx1, 0.0f) * fmaxf(yy2 - yy1, 0.0f);
    float un = aar + bar - inter;             // commutative add: matches ref exactly
    float iou = (un > 0.0f) ? inter / un : 0.0f;
    return iou >= 0.5f;
}

// ---- Kernel 1: 64-anchor tile per block. Coalesced global->LDS stage of cls,
//      4-thread/anchor argmax from LDS, decode+emit+compact on t==0 lanes.
//      Valid-count: per-block plain store (NO global atomic). cnt: padded 128B/image.
__global__ __launch_bounds__(256) void k_map(const float* __restrict__ cls,
                                             const float* __restrict__ reg,
                                             const float* __restrict__ anc,
                                             unsigned long long* __restrict__ keys,
                                             unsigned long long* __restrict__ boxes,
                                             ulonglong2* __restrict__ cand,
                                             unsigned int* __restrict__ cnt_p,
                                             unsigned int* __restrict__ vws) {
    __shared__ float4 sc[TILE * ST4];   // 21504 B
    __shared__ unsigned s_v[4];
    const int b = blockIdx.y;
    const int n0 = blockIdx.x * TILE;
    const int ait = min(TILE, NA - n0);
    const int tid = threadIdx.x;
    const size_t base4 = ((size_t)b * NA + n0) * (NC / 4);
    const int nq = ait * (NC / 4);

    // stage: 5 lane-contiguous float4 loads per thread -> LDS (padded rows)
#pragma unroll
    for (int k = 0; k < 5; ++k) {
        int q = tid + k * 256;
        if (q < nq) {
            float4 v = reinterpret_cast<const float4*>(cls)[base4 + q];
            sc[(q / 20) * ST4 + (q % 20)] = v;
        }
    }
    __syncthreads();

    // quarter-reduce: 4 threads per anchor, 20 classes each (5x ds_read_b128)
    const int a = tid >> 2, t = tid & 3;
    float best = -1.0f; int bc = 0;
#pragma unroll
    for (int j = 0; j < 5; ++j) {
        float4 v = sc[a * ST4 + t * 5 + j];
        if (v.x > best) { best = v.x; bc = t * 20 + 4 * j + 0; }
        if (v.y > best) { best = v.y; bc = t * 20 + 4 * j + 1; }
        if (v.z > best) { best = v.z; bc = t * 20 + 4 * j + 2; }
        if (v.w > best) { best = v.w; bc = t * 20 + 4 * j + 3; }
    }
    // pack: non-negative scores -> bits monotone; tie -> smallest class wins
    unsigned long long pk = ((unsigned long long)__float_as_uint(best) << 8)
                          | (unsigned)(255 - bc);
    pk = max(pk, shfl_xor_u64(pk, 1));
    pk = max(pk, shfl_xor_u64(pk, 2));

    bool valid = false, sel = false;
    unsigned long long key = 0ull, bp = 0ull;
    if (t == 0 && a < ait) {
        unsigned sbits = (unsigned)(pk >> 8);
        int cg = 255 - (int)(pk & 0xFFull);
        const int n_img = n0 + a;
        const size_t n = (size_t)b * NA + n_img;
        float4 rg = reinterpret_cast<const float4*>(reg)[n];
        float4 an = reinterpret_cast<const float4*>(anc)[n];

        // decode — _rn intrinsics to forbid FMA contraction (match XLA mul+add).
        // Byte-identical to R1/R2/R4 (verified absmax=0.0).
        float wx = __fsub_rn(an.z, an.x);
        float wy = __fsub_rn(an.w, an.y);
        float cx = __fadd_rn(an.x, __fmul_rn(0.5f, wx));
        float cy = __fadd_rn(an.y, __fmul_rn(0.5f, wy));
        float tx = __fmul_rn(rg.x, 0.1f), ty = __fmul_rn(rg.y, 0.1f);
        float tw = __fmul_rn(rg.z, 0.2f), th = __fmul_rn(rg.w, 0.2f);
        float pw = __fmul_rn(expf(tw), wx);
        float ph = __fmul_rn(expf(th), wy);
        float px = __fadd_rn(__fmul_rn(tx, wx), cx);
        float py = __fadd_rn(__fmul_rn(ty, wy), cy);
        int x1 = (int)__fsub_rn(px, __fmul_rn(0.5f, pw));
        int y1 = (int)__fsub_rn(py, __fmul_rn(0.5f, ph));
        int x2 = (int)__fadd_rn(px, __fmul_rn(0.5f, pw));
        int y2 = (int)__fadd_rn(py, __fmul_rn(0.5f, ph));
        x1 = max(x1, 0); y1 = max(y1, 0); x2 = min(x2, 639); y2 = min(y2, 639);

        bp = (unsigned long long)(unsigned short)(short)x1
           | ((unsigned long long)(unsigned short)(short)y1 << 16)
           | ((unsigned long long)(unsigned short)(short)x2 << 32)
           | ((unsigned long long)(unsigned short)(short)y2 << 48);
        float bestf = __uint_as_float(sbits);
        if (bestf > 0.05f) {  // MIN_SCORE strict
            unsigned inv = 0x1FFFFu - (unsigned)n_img;  // index asc tie-break under desc sort
            key = ((unsigned long long)sbits << 32) | ((unsigned long long)inv << 7)
                | (unsigned)cg;
            valid = true;
            sel = sbits >= FTHR;
        }
        keys[n] = key;
        boxes[n] = bp;
    }

    const int lane = tid & 63;
    const int wid = tid >> 6;

    // valid count: wave ballot -> LDS -> one plain store per block (no atomic)
    unsigned long long bal = __ballot(valid);
    if (lane == 0) s_v[wid] = (unsigned)__popcll(bal);

    // compaction: per-wave atomic to padded per-image counter (128B line each)
    unsigned long long sbal = __ballot(sel);
    unsigned base = 0;
    if (lane == 0 && sbal) base = atomicAdd(&cnt_p[b * 32], (unsigned)__popcll(sbal));
    base = __shfl(base, 0);
    if (sel) {
        unsigned off = base + (unsigned)__popcll(sbal & ((1ull << lane) - 1ull));
        if (off < CAP) {
            ulonglong2 e; e.x = key; e.y = bp;
            cand[(size_t)b * CAP + off] = e;
        }
    }

    __syncthreads();
    if (tid == 0)
        vws[(size_t)b * NBLK + blockIdx.x] = s_v[0] + s_v[1] + s_v[2] + s_v[3];
}

// ---- Kernel 2: per-image valid-sum + bitonic sort (LDS) + greedy walk + emit
__global__ __launch_bounds__(512) void k_nms(const ulonglong2* __restrict__ cand,
                                             const unsigned int* __restrict__ cnt_p,
                                             const unsigned int* __restrict__ vws,
                                             unsigned int* __restrict__ flag,
                                             float* __restrict__ out) {
    __shared__ unsigned long long sk[CAP];
    __shared__ unsigned long long sb[CAP];
    __shared__ int s_np;
    __shared__ unsigned s_ws[8];
    __shared__ unsigned s_vsum;
    const int b = blockIdx.x;
    unsigned total = cnt_p[b * 32];
    bool overflow = total > CAP;
    unsigned m = overflow ? CAP : total;

    // sum per-block valid counts (replaces the old vcnt atomic)
    unsigned local = 0;
    for (int j = threadIdx.x; j < NBLK; j += 512) local += vws[(size_t)b * NBLK + j];
    for (int o = 32; o > 0; o >>= 1) local += __shfl_down(local, o);
    if ((threadIdx.x & 63) == 0) s_ws[threadIdx.x >> 6] = local;

    for (int i = threadIdx.x; i < CAP; i += 512) {
        if (i < (int)m) { ulonglong2 e = cand[(size_t)b * CAP + i]; sk[i] = e.x; sb[i] = e.y; }
        else            { sk[i] = 0ull; sb[i] = 0ull; }
    }
    __syncthreads();
    if (threadIdx.x == 0) {
        unsigned s = 0;
        for (int w = 0; w < 8; ++w) s += s_ws[w];
        s_vsum = s;
    }

    // bitonic sort, descending by key; 512 threads = exactly one pair each
    for (int k = 2; k <= CAP; k <<= 1) {
        for (int j = k >> 1; j > 0; j >>= 1) {
            __syncthreads();
            int t = threadIdx.x;
            int i = ((t & ~(j - 1)) << 1) | (t & (j - 1));
            int l = i | j;
            unsigned long long ki = sk[i], kl = sk[l];
            bool desc = (i & k) == 0;
            if (desc ? (ki < kl) : (ki > kl)) {
                sk[i] = kl; sk[l] = ki;
                unsigned long long tmp = sb[i]; sb[i] = sb[l]; sb[l] = tmp;
            }
        }
    }
    __syncthreads();

    // greedy walk on wave 0; picked state distributed in registers (2 slots/lane);
    // next key/box prefetched to hide LDS latency
    if (threadIdx.x < 64) {
        const int lane = threadIdx.x;
        float q0x1 = 0, q0y1 = 0, q0x2 = 0, q0y2 = 0, q0a = 0; int q0c = -1;
        float q1x1 = 0, q1y1 = 0, q1x2 = 0, q1y2 = 0, q1a = 0; int q1c = -1;
        int np = 0;
        unsigned long long nk = (m > 0) ? sk[0] : 0ull;
        unsigned long long nbx = (m > 0) ? sb[0] : 0ull;
        for (int jj = 0; jj < (int)m && np < MAXDET; ++jj) {
            unsigned long long key = nk;
            unsigned long long bx = nbx;
            if (jj + 1 < (int)m) { nk = sk[jj + 1]; nbx = sb[jj + 1]; }
            if (!key) break;
            int ci = (int)(key & 0x7Full);
            float x1 = (float)(short)(bx & 0xFFFF);
            float y1 = (float)(short)((bx >> 16) & 0xFFFF);
            float x2 = (float)(short)((bx >> 32) & 0xFFFF);
            float y2 = (float)(short)((bx >> 48) & 0xFFFF);
            float ar = (x2 - x1) * (y2 - y1);
            bool sup = false;
            if (lane < np && q0c == ci)
                sup = iou_ge_half(q0x1, q0y1, q0x2, q0y2, q0a, x1, y1, x2, y2, ar);
            if (64 + lane < np && q1c == ci)
                sup = sup || iou_ge_half(q1x1, q1y1, q1x2, q1y2, q1a, x1, y1, x2, y2, ar);
            if (__ballot(sup) != 0ull) continue;
            int s = np;
            if (s < 64) {
                if (lane == s) {
                    q0x1 = x1; q0y1 = y1; q0x2 = x2; q0y2 = y2; q0a = ar; q0c = ci;
                    out[b * MAXDET + s] = __uint_as_float((unsigned)(key >> 32));
                    out[NB * MAXDET + b * MAXDET + s] = (float)ci;
                    float* ob = out + 2 * NB * MAXDET + (size_t)(b * MAXDET + s) * 4;
                    ob[0] = x1; ob[1] = y1; ob[2] = x2; ob[3] = y2;
                }
            } else {
                if (lane == s - 64) {
                    q1x1 = x1; q1y1 = y1; q1x2 = x2; q1y2 = y2; q1a = ar; q1c = ci;
                    out[b * MAXDET + s] = __uint_as_float((unsigned)(key >> 32));
                    out[NB * MAXDET + b * MAXDET + s] = (float)ci;
                    float* ob = out + 2 * NB * MAXDET + (size_t)(b * MAXDET + s) * 4;
                    ob[0] = x1; ob[1] = y1; ob[2] = x2; ob[3] = y2;
                }
            }
            ++np;
        }
        if (lane == 0) s_np = np;
    }
    __syncthreads();
    int np = s_np;
    // fallback iff candidates were dropped (overflow) or walk exhausted with unseen valid cands
    bool fb = overflow || (np < MAXDET && s_vsum > m);
    if (threadIdx.x == 0) flag[b] = fb ? 1u : 0u;
    if (!fb) {
        for (int i = np + (int)threadIdx.x; i < MAXDET; i += 512) {
            out[b * MAXDET + i] = -1.0f;
            out[NB * MAXDET + b * MAXDET + i] = -1.0f;
            float* ob = out + 2 * NB * MAXDET + (size_t)(b * MAXDET + i) * 4;
            ob[0] = -1.0f; ob[1] = -1.0f; ob[2] = -1.0f; ob[3] = -1.0f;
        }
    }
}

// ---- Kernel 3: exact slow fallback (reference algorithm); no-op unless flag[b]
__global__ __launch_bounds__(1024) void k_fallback(unsigned long long* __restrict__ keys,
                                                   const unsigned long long* __restrict__ boxes,
                                                   const unsigned int* __restrict__ flag,
                                                   float* __restrict__ out) {
    const int b = blockIdx.x;
    if (!flag[b]) return;
    __shared__ unsigned long long wm[16];
    __shared__ unsigned long long gbest;
    unsigned long long* kb = keys + (size_t)b * NA;
    const unsigned long long* bb = boxes + (size_t)b * NA;

    for (int it = 0; it < MAXDET; ++it) {
        unsigned long long best = 0ull;
        for (int i = threadIdx.x; i < NA; i += 1024) {
            unsigned long long k = kb[i];
            if (k > best) best = k;
        }
        for (int o = 32; o > 0; o >>= 1) {
            unsigned long long v = shfl_down_u64(best, o);
            if (v > best) best = v;
        }
        if ((threadIdx.x & 63) == 0) wm[threadIdx.x >> 6] = best;
        __syncthreads();
        if (threadIdx.x == 0) {
            unsigned long long g = wm[0];
            for (int w = 1; w < 16; ++w) if (wm[w] > g) g = wm[w];
            gbest = g;
        }
        __syncthreads();
        best = gbest;
        if (best == 0ull) {
            for (int s = it + (int)threadIdx.x; s < MAXDET; s += 1024) {
                out[b * MAXDET + s] = -1.0f;
                out[NB * MAXDET + b * MAXDET + s] = -1.0f;
                float* ob = out + 2 * NB * MAXDET + (size_t)(b * MAXDET + s) * 4;
                ob[0] = -1.0f; ob[1] = -1.0f; ob[2] = -1.0f; ob[3] = -1.0f;
            }
            break;
        }
        int ci = (int)(best & 0x7Full);
        int a = 0x1FFFF - (int)((best >> 7) & 0x1FFFFull);
        unsigned long long bx = bb[a];
        float x1 = (float)(short)(bx & 0xFFFF);
        float y1 = (float)(short)((bx >> 16) & 0xFFFF);
        float x2 = (float)(short)((bx >> 32) & 0xFFFF);
        float y2 = (float)(short)((bx >> 48) & 0xFFFF);
        float ar = (x2 - x1) * (y2 - y1);
        if (threadIdx.x == 0) {
            out[b * MAXDET + it] = __uint_as_float((unsigned)(best >> 32));
            out[NB * MAXDET + b * MAXDET + it] = (float)ci;
            float* ob = out + 2 * NB * MAXDET + (size_t)(b * MAXDET + it) * 4;
            ob[0] = x1; ob[1] = y1; ob[2] = x2; ob[3] = y2;
        }
        for (int i = threadIdx.x; i < NA; i += 1024) {
            unsigned long long kk = kb[i];
            if (!kk) continue;
            if (kk == best) { kb[i] = 0ull; continue; }
            if ((int)(kk & 0x7Full) != ci) continue;
            unsigned long long ob2 = bb[i];
            float u1 = (float)(short)(ob2 & 0xFFFF);
            float v1 = (float)(short)((ob2 >> 16) & 0xFFFF);
            float u2 = (float)(short)((ob2 >> 32) & 0xFFFF);
            float v2 = (float)(short)((ob2 >> 48) & 0xFFFF);
            float oar = (u2 - u1) * (v2 - v1);
            if (iou_ge_half(x1, y1, x2, y2, ar, u1, v1, u2, v2, oar)) kb[i] = 0ull;
        }
        __syncthreads();
    }
}

extern "C" void kernel_launch(void* const* d_in, const int* in_sizes, int n_in,
                              void* d_out, int out_size, void* d_ws, size_t ws_size,
                              hipStream_t stream) {
    const float* cls = (const float*)d_in[0];
    const float* reg = (const float*)d_in[1];
    const float* anc = (const float*)d_in[2];
    float* out = (float*)d_out;

    const size_t SZ_KEYS = (size_t)NB * NA * 8;               // 4,910,400 B
    unsigned long long* keys  = (unsigned long long*)d_ws;
    unsigned long long* boxes = (unsigned long long*)((char*)d_ws + SZ_KEYS);
    ulonglong2* cand = (ulonglong2*)((char*)d_ws + 2 * SZ_KEYS);          // 16-aligned
    unsigned* cnt_p = (unsigned*)((char*)d_ws + 2 * SZ_KEYS + (size_t)NB * CAP * 16);
    unsigned* vws   = cnt_p + NB * 32;                                    // [NB][NBLK]
    unsigned* flag  = vws + (size_t)NB * NBLK;

    // zero compaction counters (8 images x 128B-padded) = 1KB
    hipMemsetAsync(cnt_p, 0, NB * 32 * 4, stream);

    dim3 gmap(NBLK, NB);
    k_map<<<gmap, 256, 0, stream>>>(cls, reg, anc, keys, boxes, cand, cnt_p, vws);
    k_nms<<<NB, 512, 0, stream>>>(cand, cnt_p, vws, flag, out);
    k_fallback<<<NB, 1024, 0, stream>>>(keys, boxes, flag, out);
}

// Round 6
// 333.028 us; speedup vs baseline: 2.2701x; 1.0023x over previous
//
#include <hip/hip_runtime.h>

// RetinaNet decode + per-class NMS (exact reference semantics).
// Pipeline: memset(cnt_p 1KB) -> k_map (persistent, reg-prefetch double-staged)
//           -> k_nms (vsum + sort + walk) -> k_fallback (exact, no-op unless flagged)
#define NB 8
#define NA 76725
#define NC 80
#define MAXDET 100
#define CAP  1024          // compaction buffer capacity per image
#define FTHR 0x3F7FF994u   // float bits of ~0.999902: E[count]/image ~600 (max of 80 U(0,1))
#define TILE 64            // anchors per tile in k_map
#define NBLK 1199          // (NA + TILE - 1) / TILE  (tiles per image)
#define GX   192           // persistent blocks per image; each walks ~6-7 tiles
#define ST4  21            // LDS row stride in float4 (84 dwords = 80 + 4 pad)

__device__ inline unsigned long long shfl_down_u64(unsigned long long v, int o) {
    unsigned lo = (unsigned)v, hi = (unsigned)(v >> 32);
    lo = __shfl_down(lo, o);
    hi = __shfl_down(hi, o);
    return ((unsigned long long)hi << 32) | lo;
}

__device__ inline unsigned long long shfl_xor_u64(unsigned long long v, int m) {
    unsigned lo = __shfl_xor((unsigned)v, m), hi = __shfl_xor((unsigned)(v >> 32), m);
    return ((unsigned long long)hi << 32) | lo;
}

__device__ inline bool iou_ge_half(float ax1, float ay1, float ax2, float ay2, float aar,
                                   float bx1, float by1, float bx2, float by2, float bar) {
    float xx1 = fmaxf(ax1, bx1), yy1 = fmaxf(ay1, by1);
    float xx2 = fminf(ax2, bx2), yy2 = fminf(ay2, by2);
    float inter = fmaxf(xx2 - xx1, 0.0f) * fmaxf(yy2 - yy1, 0.0f);
    float un = aar + bar - inter;             // commutative add: matches ref exactly
    float iou = (un > 0.0f) ? inter / un : 0.0f;
    return iou >= 0.5f;
}

// ---- Kernel 1: persistent 64-anchor tiles. Per iteration: regs->LDS store of
//      prefetched tile, prefetch next tile's cls(+reg/anc) into regs, compute
//      current tile from LDS (argmax, decode, compact). No same-line atomics.
__global__ __launch_bounds__(256) void k_map(const float* __restrict__ cls,
                                             const float* __restrict__ reg,
                                             const float* __restrict__ anc,
                                             unsigned long long* __restrict__ keys,
                                             unsigned long long* __restrict__ boxes,
                                             ulonglong2* __restrict__ cand,
                                             unsigned int* __restrict__ cnt_p,
                                             unsigned int* __restrict__ vws) {
    __shared__ float4 sc[TILE * ST4];   // 21504 B
    __shared__ float4 s_rg[TILE];       // 1024 B
    __shared__ float4 s_an[TILE];       // 1024 B
    __shared__ unsigned s_v[4];
    const int b = blockIdx.y;
    const int tid = threadIdx.x;
    const int lane = tid & 63;
    const int wid = tid >> 6;
    const float4* cls4 = reinterpret_cast<const float4*>(cls);
    const float4* reg4 = reinterpret_cast<const float4*>(reg);
    const float4* anc4 = reinterpret_cast<const float4*>(anc);

    int tile = blockIdx.x;
    int n0 = tile * TILE;
    int ait = min(TILE, NA - n0);
    int nq = ait * 20;
    size_t base4 = ((size_t)b * NA + n0) * 20;

    // prologue prefetch: cls tile (5 x float4/thread) + reg/anc tile (1 float4)
    float4 r0, r1, r2, r3, r4, ra;
#define LOADQ(K, RK) { int q = tid + (K)*256; if (q < nq) RK = cls4[base4 + q]; }
    LOADQ(0, r0) LOADQ(1, r1) LOADQ(2, r2) LOADQ(3, r3) LOADQ(4, r4)
    if (tid < 64) { if (tid < ait) ra = reg4[(size_t)b * NA + n0 + tid]; }
    else if (tid < 128) { if (tid - 64 < ait) ra = anc4[(size_t)b * NA + n0 + tid - 64]; }

    unsigned vacc = 0;
    for (;;) {
        __syncthreads();   // prior compute done reading LDS
        // store prefetched tile -> LDS
#define STQ(K, RK) { int q = tid + (K)*256; if (q < nq) sc[(q / 20) * ST4 + (q % 20)] = RK; }
        STQ(0, r0) STQ(1, r1) STQ(2, r2) STQ(3, r3) STQ(4, r4)
        if (tid < 64) { if (tid < ait) s_rg[tid] = ra; }
        else if (tid < 128) { if (tid - 64 < ait) s_an[tid - 64] = ra; }
        __syncthreads();

        const int cn0 = n0, cait = ait;   // tile being computed

        // advance + prefetch next tile (loads fly under the compute below)
        tile += GX;
        const bool more = tile < NBLK;
        if (more) {
            n0 = tile * TILE;
            ait = min(TILE, NA - n0);
            nq = ait * 20;
            base4 = ((size_t)b * NA + n0) * 20;
            LOADQ(0, r0) LOADQ(1, r1) LOADQ(2, r2) LOADQ(3, r3) LOADQ(4, r4)
            if (tid < 64) { if (tid < ait) ra = reg4[(size_t)b * NA + n0 + tid]; }
            else if (tid < 128) { if (tid - 64 < ait) ra = anc4[(size_t)b * NA + n0 + tid - 64]; }
        }

        // compute: quarter-reduce argmax (4 threads/anchor, 5x ds_read_b128 each)
        const int a = tid >> 2, t = tid & 3;
        float best = -1.0f; int bc = 0;
#pragma unroll
        for (int j = 0; j < 5; ++j) {
            float4 v = sc[a * ST4 + t * 5 + j];
            if (v.x > best) { best = v.x; bc = t * 20 + 4 * j + 0; }
            if (v.y > best) { best = v.y; bc = t * 20 + 4 * j + 1; }
            if (v.z > best) { best = v.z; bc = t * 20 + 4 * j + 2; }
            if (v.w > best) { best = v.w; bc = t * 20 + 4 * j + 3; }
        }
        // pack: non-negative scores -> bits monotone; tie -> smallest class wins
        unsigned long long pk = ((unsigned long long)__float_as_uint(best) << 8)
                              | (unsigned)(255 - bc);
        pk = max(pk, shfl_xor_u64(pk, 1));
        pk = max(pk, shfl_xor_u64(pk, 2));

        bool valid = false, sel = false;
        unsigned long long key = 0ull, bp = 0ull;
        if (t == 0 && a < cait) {
            unsigned sbits = (unsigned)(pk >> 8);
            int cg = 255 - (int)(pk & 0xFFull);
            const int n_img = cn0 + a;
            const size_t n = (size_t)b * NA + n_img;
            float4 rg = s_rg[a];
            float4 an = s_an[a];

            // decode — _rn intrinsics to forbid FMA contraction (match XLA mul+add).
            // Byte-identical to R1..R5 (verified absmax=0.0).
            float wx = __fsub_rn(an.z, an.x);
            float wy = __fsub_rn(an.w, an.y);
            float cx = __fadd_rn(an.x, __fmul_rn(0.5f, wx));
            float cy = __fadd_rn(an.y, __fmul_rn(0.5f, wy));
            float tx = __fmul_rn(rg.x, 0.1f), ty = __fmul_rn(rg.y, 0.1f);
            float tw = __fmul_rn(rg.z, 0.2f), th = __fmul_rn(rg.w, 0.2f);
            float pw = __fmul_rn(expf(tw), wx);
            float ph = __fmul_rn(expf(th), wy);
            float px = __fadd_rn(__fmul_rn(tx, wx), cx);
            float py = __fadd_rn(__fmul_rn(ty, wy), cy);
            int x1 = (int)__fsub_rn(px, __fmul_rn(0.5f, pw));
            int y1 = (int)__fsub_rn(py, __fmul_rn(0.5f, ph));
            int x2 = (int)__fadd_rn(px, __fmul_rn(0.5f, pw));
            int y2 = (int)__fadd_rn(py, __fmul_rn(0.5f, ph));
            x1 = max(x1, 0); y1 = max(y1, 0); x2 = min(x2, 639); y2 = min(y2, 639);

            bp = (unsigned long long)(unsigned short)(short)x1
               | ((unsigned long long)(unsigned short)(short)y1 << 16)
               | ((unsigned long long)(unsigned short)(short)x2 << 32)
               | ((unsigned long long)(unsigned short)(short)y2 << 48);
            float bestf = __uint_as_float(sbits);
            if (bestf > 0.05f) {  // MIN_SCORE strict
                unsigned inv = 0x1FFFFu - (unsigned)n_img;  // index asc tie-break
                key = ((unsigned long long)sbits << 32) | ((unsigned long long)inv << 7)
                    | (unsigned)cg;
                valid = true;
                sel = sbits >= FTHR;
            }
            keys[n] = key;
            boxes[n] = bp;
        }

        // valid count: ballot -> register accumulator (no atomic)
        unsigned long long bal = __ballot(valid);
        if (lane == 0) vacc += (unsigned)__popcll(bal);

        // compaction: per-wave atomic to padded per-image counter (128B line each)
        unsigned long long sbal = __ballot(sel);
        unsigned base = 0;
        if (lane == 0 && sbal) base = atomicAdd(&cnt_p[b * 32], (unsigned)__popcll(sbal));
        base = __shfl(base, 0);
        if (sel) {
            unsigned off = base + (unsigned)__popcll(sbal & ((1ull << lane) - 1ull));
            if (off < CAP) {
                ulonglong2 e; e.x = key; e.y = bp;
                cand[(size_t)b * CAP + off] = e;
            }
        }

        if (!more) break;
    }

    if (lane == 0) s_v[wid] = vacc;
    __syncthreads();
    if (tid == 0)
        vws[(size_t)b * GX + blockIdx.x] = s_v[0] + s_v[1] + s_v[2] + s_v[3];
}

// ---- Kernel 2: per-image valid-sum + bitonic sort (LDS) + greedy walk + emit
__global__ __launch_bounds__(512) void k_nms(const ulonglong2* __restrict__ cand,
                                             const unsigned int* __restrict__ cnt_p,
                                             const unsigned int* __restrict__ vws,
                                             unsigned int* __restrict__ flag,
                                             float* __restrict__ out) {
    __shared__ unsigned long long sk[CAP];
    __shared__ unsigned long long sb[CAP];
    __shared__ int s_np;
    __shared__ unsigned s_ws[8];
    __shared__ unsigned s_vsum;
    const int b = blockIdx.x;
    unsigned total = cnt_p[b * 32];
    bool overflow = total > CAP;
    unsigned m = overflow ? CAP : total;

    // sum per-block valid counts
    unsigned local = 0;
    for (int j = threadIdx.x; j < GX; j += 512) local += vws[(size_t)b * GX + j];
    for (int o = 32; o > 0; o >>= 1) local += __shfl_down(local, o);
    if ((threadIdx.x & 63) == 0) s_ws[threadIdx.x >> 6] = local;

    for (int i = threadIdx.x; i < CAP; i += 512) {
        if (i < (int)m) { ulonglong2 e = cand[(size_t)b * CAP + i]; sk[i] = e.x; sb[i] = e.y; }
        else            { sk[i] = 0ull; sb[i] = 0ull; }
    }
    __syncthreads();
    if (threadIdx.x == 0) {
        unsigned s = 0;
        for (int w = 0; w < 8; ++w) s += s_ws[w];
        s_vsum = s;
    }

    // bitonic sort, descending by key; 512 threads = exactly one pair each
    for (int k = 2; k <= CAP; k <<= 1) {
        for (int j = k >> 1; j > 0; j >>= 1) {
            __syncthreads();
            int t = threadIdx.x;
            int i = ((t & ~(j - 1)) << 1) | (t & (j - 1));
            int l = i | j;
            unsigned long long ki = sk[i], kl = sk[l];
            bool desc = (i & k) == 0;
            if (desc ? (ki < kl) : (ki > kl)) {
                sk[i] = kl; sk[l] = ki;
                unsigned long long tmp = sb[i]; sb[i] = sb[l]; sb[l] = tmp;
            }
        }
    }
    __syncthreads();

    // greedy walk on wave 0; picked state distributed in registers (2 slots/lane);
    // next key/box prefetched to hide LDS latency
    if (threadIdx.x < 64) {
        const int lane = threadIdx.x;
        float q0x1 = 0, q0y1 = 0, q0x2 = 0, q0y2 = 0, q0a = 0; int q0c = -1;
        float q1x1 = 0, q1y1 = 0, q1x2 = 0, q1y2 = 0, q1a = 0; int q1c = -1;
        int np = 0;
        unsigned long long nk = (m > 0) ? sk[0] : 0ull;
        unsigned long long nbx = (m > 0) ? sb[0] : 0ull;
        for (int jj = 0; jj < (int)m && np < MAXDET; ++jj) {
            unsigned long long key = nk;
            unsigned long long bx = nbx;
            if (jj + 1 < (int)m) { nk = sk[jj + 1]; nbx = sb[jj + 1]; }
            if (!key) break;
            int ci = (int)(key & 0x7Full);
            float x1 = (float)(short)(bx & 0xFFFF);
            float y1 = (float)(short)((bx >> 16) & 0xFFFF);
            float x2 = (float)(short)((bx >> 32) & 0xFFFF);
            float y2 = (float)(short)((bx >> 48) & 0xFFFF);
            float ar = (x2 - x1) * (y2 - y1);
            bool sup = false;
            if (lane < np && q0c == ci)
                sup = iou_ge_half(q0x1, q0y1, q0x2, q0y2, q0a, x1, y1, x2, y2, ar);
            if (64 + lane < np && q1c == ci)
                sup = sup || iou_ge_half(q1x1, q1y1, q1x2, q1y2, q1a, x1, y1, x2, y2, ar);
            if (__ballot(sup) != 0ull) continue;
            int s = np;
            if (s < 64) {
                if (lane == s) {
                    q0x1 = x1; q0y1 = y1; q0x2 = x2; q0y2 = y2; q0a = ar; q0c = ci;
                    out[b * MAXDET + s] = __uint_as_float((unsigned)(key >> 32));
                    out[NB * MAXDET + b * MAXDET + s] = (float)ci;
                    float* ob = out + 2 * NB * MAXDET + (size_t)(b * MAXDET + s) * 4;
                    ob[0] = x1; ob[1] = y1; ob[2] = x2; ob[3] = y2;
                }
            } else {
                if (lane == s - 64) {
                    q1x1 = x1; q1y1 = y1; q1x2 = x2; q1y2 = y2; q1a = ar; q1c = ci;
                    out[b * MAXDET + s] = __uint_as_float((unsigned)(key >> 32));
                    out[NB * MAXDET + b * MAXDET + s] = (float)ci;
                    float* ob = out + 2 * NB * MAXDET + (size_t)(b * MAXDET + s) * 4;
                    ob[0] = x1; ob[1] = y1; ob[2] = x2; ob[3] = y2;
                }
            }
            ++np;
        }
        if (lane == 0) s_np = np;
    }
    __syncthreads();
    int np = s_np;
    // fallback iff candidates were dropped (overflow) or walk exhausted with unseen valid cands
    bool fb = overflow || (np < MAXDET && s_vsum > m);
    if (threadIdx.x == 0) flag[b] = fb ? 1u : 0u;
    if (!fb) {
        for (int i = np + (int)threadIdx.x; i < MAXDET; i += 512) {
            out[b * MAXDET + i] = -1.0f;
            out[NB * MAXDET + b * MAXDET + i] = -1.0f;
            float* ob = out + 2 * NB * MAXDET + (size_t)(b * MAXDET + i) * 4;
            ob[0] = -1.0f; ob[1] = -1.0f; ob[2] = -1.0f; ob[3] = -1.0f;
        }
    }
}

// ---- Kernel 3: exact slow fallback (reference algorithm); no-op unless flag[b]
__global__ __launch_bounds__(1024) void k_fallback(unsigned long long* __restrict__ keys,
                                                   const unsigned long long* __restrict__ boxes,
                                                   const unsigned int* __restrict__ flag,
                                                   float* __restrict__ out) {
    const int b = blockIdx.x;
    if (!flag[b]) return;
    __shared__ unsigned long long wm[16];
    __shared__ unsigned long long gbest;
    unsigned long long* kb = keys + (size_t)b * NA;
    const unsigned long long* bb = boxes + (size_t)b * NA;

    for (int it = 0; it < MAXDET; ++it) {
        unsigned long long best = 0ull;
        for (int i = threadIdx.x; i < NA; i += 1024) {
            unsigned long long k = kb[i];
            if (k > best) best = k;
        }
        for (int o = 32; o > 0; o >>= 1) {
            unsigned long long v = shfl_down_u64(best, o);
            if (v > best) best = v;
        }
        if ((threadIdx.x & 63) == 0) wm[threadIdx.x >> 6] = best;
        __syncthreads();
        if (threadIdx.x == 0) {
            unsigned long long g = wm[0];
            for (int w = 1; w < 16; ++w) if (wm[w] > g) g = wm[w];
            gbest = g;
        }
        __syncthreads();
        best = gbest;
        if (best == 0ull) {
            for (int s = it + (int)threadIdx.x; s < MAXDET; s += 1024) {
                out[b * MAXDET + s] = -1.0f;
                out[NB * MAXDET + b * MAXDET + s] = -1.0f;
                float* ob = out + 2 * NB * MAXDET + (size_t)(b * MAXDET + s) * 4;
                ob[0] = -1.0f; ob[1] = -1.0f; ob[2] = -1.0f; ob[3] = -1.0f;
            }
            break;
        }
        int ci = (int)(best & 0x7Full);
        int a = 0x1FFFF - (int)((best >> 7) & 0x1FFFFull);
        unsigned long long bx = bb[a];
        float x1 = (float)(short)(bx & 0xFFFF);
        float y1 = (float)(short)((bx >> 16) & 0xFFFF);
        float x2 = (float)(short)((bx >> 32) & 0xFFFF);
        float y2 = (float)(short)((bx >> 48) & 0xFFFF);
        float ar = (x2 - x1) * (y2 - y1);
        if (threadIdx.x == 0) {
            out[b * MAXDET + it] = __uint_as_float((unsigned)(best >> 32));
            out[NB * MAXDET + b * MAXDET + it] = (float)ci;
            float* ob = out + 2 * NB * MAXDET + (size_t)(b * MAXDET + it) * 4;
            ob[0] = x1; ob[1] = y1; ob[2] = x2; ob[3] = y2;
        }
        for (int i = threadIdx.x; i < NA; i += 1024) {
            unsigned long long kk = kb[i];
            if (!kk) continue;
            if (kk == best) { kb[i] = 0ull; continue; }
            if ((int)(kk & 0x7Full) != ci) continue;
            unsigned long long ob2 = bb[i];
            float u1 = (float)(short)(ob2 & 0xFFFF);
            float v1 = (float)(short)((ob2 >> 16) & 0xFFFF);
            float u2 = (float)(short)((ob2 >> 32) & 0xFFFF);
            float v2 = (float)(short)((ob2 >> 48) & 0xFFFF);
            float oar = (u2 - u1) * (v2 - v1);
            if (iou_ge_half(x1, y1, x2, y2, ar, u1, v1, u2, v2, oar)) kb[i] = 0ull;
        }
        __syncthreads();
    }
}

extern "C" void kernel_launch(void* const* d_in, const int* in_sizes, int n_in,
                              void* d_out, int out_size, void* d_ws, size_t ws_size,
                              hipStream_t stream) {
    const float* cls = (const float*)d_in[0];
    const float* reg = (const float*)d_in[1];
    const float* anc = (const float*)d_in[2];
    float* out = (float*)d_out;

    const size_t SZ_KEYS = (size_t)NB * NA * 8;               // 4,910,400 B
    unsigned long long* keys  = (unsigned long long*)d_ws;
    unsigned long long* boxes = (unsigned long long*)((char*)d_ws + SZ_KEYS);
    ulonglong2* cand = (ulonglong2*)((char*)d_ws + 2 * SZ_KEYS);          // 16-aligned
    unsigned* cnt_p = (unsigned*)((char*)d_ws + 2 * SZ_KEYS + (size_t)NB * CAP * 16);
    unsigned* vws   = cnt_p + NB * 32;                                    // [NB][GX]
    unsigned* flag  = vws + (size_t)NB * GX;

    // zero compaction counters (8 images x 128B-padded) = 1KB
    hipMemsetAsync(cnt_p, 0, NB * 32 * 4, stream);

    dim3 gmap(GX, NB);
    k_map<<<gmap, 256, 0, stream>>>(cls, reg, anc, keys, boxes, cand, cnt_p, vws);
    k_nms<<<NB, 512, 0, stream>>>(cand, cnt_p, vws, flag, out);
    k_fallback<<<NB, 1024, 0, stream>>>(keys, boxes, flag, out);
}